// Round 7
// baseline (899.649 us; speedup 1.0000x reference)
//
#include <hip/hip_runtime.h>
#include <math.h>

#define NPG    1024
#define KNN    20
#define NGRAPH 64
#define NTOT   (NGRAPH * NPG)   // 65536
#define HD     16
#define NPB    32               // nodes per layer-block
#define TPB    320              // 32 nodes * 10 pairs
#define SMSTR  17               // padded LDS row stride

#define SCN    4                // knn scanners per node
#define NLB    128              // knn nodes per block

typedef float v2f __attribute__((ext_vector_type(2)));

#define CSPACE __attribute__((address_space(4)))
__device__ __forceinline__ const CSPACE float* cptr(const float* p) {
    return (const CSPACE float*)(unsigned long long)p;
}
__device__ __forceinline__ const CSPACE v2f* c2(const float* p) {
    return (const CSPACE v2f*)(unsigned long long)p;
}

__device__ __forceinline__ float silu_f(float x) {
    float e = __expf(-x);
    return x * __fdividef(1.0f, 1.0f + e);
}
__device__ __forceinline__ v2f silu2(v2f x) {
    float a = x[0], b = x[1];
    a = a * __fdividef(1.0f, 1.0f + __expf(-a));
    b = b * __fdividef(1.0f, 1.0f + __expf(-b));
    return (v2f){a, b};
}

__device__ __forceinline__ float d2_exact(float xi, float yi, float zi, float sqi,
                                          float xj, float yj, float zj, float sqj) {
    float dot = __fadd_rn(__fadd_rn(__fmul_rn(xi, xj), __fmul_rn(yi, yj)),
                          __fmul_rn(zi, zj));
    return __fsub_rn(__fadd_rn(sqi, sqj), __fmul_rn(2.0f, dot));
}

// ---------------------------------------------------------------------------
// KNN (unchanged from R5)
// ---------------------------------------------------------------------------
__global__ __launch_bounds__(512) void knn_kernel(const float* __restrict__ pos,
                                                  int* __restrict__ srcidx) {
    __shared__ float4 sp[NPG];
    __shared__ float  lists[SCN][NLB][21];
    __shared__ float  taus[NLB];
    __shared__ int    cnts[SCN][NLB];
    __shared__ int    tcnts[SCN][NLB];
    __shared__ int    ties[SCN][NLB][4];

    const int t     = threadIdx.x;
    const int g     = blockIdx.x >> 3;
    const int chunk = blockIdx.x & 7;
    const int base  = g * NPG;

    for (int u = t; u < NPG; u += 512) {
        float x = pos[(size_t)(base + u) * 3 + 0];
        float y = pos[(size_t)(base + u) * 3 + 1];
        float z = pos[(size_t)(base + u) * 3 + 2];
        float sq = __fadd_rn(__fadd_rn(__fmul_rn(x, x), __fmul_rn(y, y)),
                             __fmul_rn(z, z));
        sp[u] = make_float4(x, y, z, sq);
    }
    __syncthreads();

    const int nl = t & (NLB - 1);
    const int s  = t >> 7;
    const int li = chunk * NLB + nl;
    const float4 qi = sp[li];

    float sl[KNN];
#pragma unroll
    for (int p = 0; p < KNN; ++p) sl[p] = INFINITY;

    const int jbeg = s * 256, jend = jbeg + 256;
    for (int j0 = jbeg; j0 < jend; j0 += 4) {
        float4 qa = sp[j0 + 0];
        float4 qb = sp[j0 + 1];
        float4 qc = sp[j0 + 2];
        float4 qd = sp[j0 + 3];
        float d0 = d2_exact(qi.x, qi.y, qi.z, qi.w, qa.x, qa.y, qa.z, qa.w);
        float d1 = d2_exact(qi.x, qi.y, qi.z, qi.w, qb.x, qb.y, qb.z, qb.w);
        float d2 = d2_exact(qi.x, qi.y, qi.z, qi.w, qc.x, qc.y, qc.z, qc.w);
        float d3 = d2_exact(qi.x, qi.y, qi.z, qi.w, qd.x, qd.y, qd.z, qd.w);
        d0 = (j0 + 0 == li) ? INFINITY : d0;
        d1 = (j0 + 1 == li) ? INFINITY : d1;
        d2 = (j0 + 2 == li) ? INFINITY : d2;
        d3 = (j0 + 3 == li) ? INFINITY : d3;
        float dd[4] = {d0, d1, d2, d3};
#pragma unroll
        for (int u = 0; u < 4; ++u) {
            const float d = dd[u];
#pragma unroll
            for (int p = KNN - 1; p >= 1; --p)
                sl[p] = __builtin_amdgcn_fmed3f(sl[p - 1], d, sl[p]);
            sl[0] = fminf(sl[0], d);
        }
    }

#pragma unroll
    for (int p = 0; p < KNN; ++p) lists[s][nl][p] = sl[p];
    __syncthreads();

    if (s == 0) {
        int i0 = 0, i1 = 0, i2 = 0, i3 = 0;
        float h0 = lists[0][nl][0], h1 = lists[1][nl][0];
        float h2 = lists[2][nl][0], h3 = lists[3][nl][0];
        float cur = h0;
#pragma unroll
        for (int step = 0; step < KNN; ++step) {
            int which = 0; cur = h0;
            if (h1 < cur) { cur = h1; which = 1; }
            if (h2 < cur) { cur = h2; which = 2; }
            if (h3 < cur) { cur = h3; which = 3; }
            if (which == 0)      { ++i0; h0 = lists[0][nl][i0]; }
            else if (which == 1) { ++i1; h1 = lists[1][nl][i1]; }
            else if (which == 2) { ++i2; h2 = lists[2][nl][i2]; }
            else                 { ++i3; h3 = lists[3][nl][i3]; }
        }
        taus[nl] = cur;
    }
    __syncthreads();

    const float tau = taus[nl];
    const int outbase = (base + li) * KNN;

    int cnt = 0, tc = 0;
    int tj0 = 0, tj1 = 0, tj2 = 0, tj3 = 0;
#pragma unroll 4
    for (int j = jbeg; j < jend; ++j) {
        if (j == li) continue;
        float4 q = sp[j];
        float d = d2_exact(qi.x, qi.y, qi.z, qi.w, q.x, q.y, q.z, q.w);
        if (d < tau) ++cnt;
        else if (d == tau) {
            if (tc == 0) tj0 = j;
            else if (tc == 1) tj1 = j;
            else if (tc == 2) tj2 = j;
            else if (tc == 3) tj3 = j;
            ++tc;
        }
    }
    cnts[s][nl]  = cnt;
    tcnts[s][nl] = (tc < 4) ? tc : 4;
    ties[s][nl][0] = tj0; ties[s][nl][1] = tj1;
    ties[s][nl][2] = tj2; ties[s][nl][3] = tj3;
    __syncthreads();

    int w = outbase;
#pragma unroll
    for (int ss = 0; ss < SCN; ++ss) if (ss < s) w += cnts[ss][nl];
#pragma unroll 4
    for (int j = jbeg; j < jend; ++j) {
        if (j == li) continue;
        float4 q = sp[j];
        float d = d2_exact(qi.x, qi.y, qi.z, qi.w, q.x, q.y, q.z, q.w);
        if (d < tau) { srcidx[w] = base + j; ++w; }
    }

    if (s == 0) {
        int total = cnts[0][nl] + cnts[1][nl] + cnts[2][nl] + cnts[3][nl];
        int need = KNN - total;
        int w2 = outbase + total;
        for (int ss = 0; ss < SCN && need > 0; ++ss) {
            int tn = tcnts[ss][nl];
            for (int u = 0; u < tn && need > 0; ++u) {
                srcidx[w2] = base + ties[ss][nl][u];
                ++w2; --need;
            }
        }
    }
}

// ---------------------------------------------------------------------------
// embedding (unchanged)
// ---------------------------------------------------------------------------
__global__ __launch_bounds__(256) void embed_kernel(
    const float* __restrict__ pos,
    const float* __restrict__ w1_, const float* __restrict__ b1_,
    const float* __restrict__ w2_, const float* __restrict__ b2_,
    float* __restrict__ h) {
    const auto w1 = cptr(w1_); const auto b1 = cptr(b1_);
    const auto w2 = cptr(w2_); const auto b2 = cptr(b2_);
    const int i = blockIdx.x * 256 + threadIdx.x;
    if (i >= NTOT) return;
    const float x = pos[3 * (size_t)i + 0];
    const float y = pos[3 * (size_t)i + 1];
    const float z = pos[3 * (size_t)i + 2];

    float t[HD];
#pragma unroll
    for (int o = 0; o < HD; ++o)
        t[o] = silu_f(b1[o] + x * w1[0 * HD + o] + y * w1[1 * HD + o] + z * w1[2 * HD + o]);

    float r[HD];
#pragma unroll
    for (int o = 0; o < HD; ++o) r[o] = b2[o];
#pragma unroll
    for (int c = 0; c < HD; ++c) {
        const float a = t[c];
#pragma unroll
        for (int o = 0; o < HD; ++o) r[o] += a * w2[c * HD + o];
    }
    float4* hp = (float4*)(h + (size_t)i * HD);
    hp[0] = make_float4(r[0], r[1], r[2], r[3]);
    hp[1] = make_float4(r[4], r[5], r[6], r[7]);
    hp[2] = make_float4(r[8], r[9], r[10], r[11]);
    hp[3] = make_float4(r[12], r[13], r[14], r[15]);
}

// ---------------------------------------------------------------------------
// fused layer v3: 2 edges (same dst node) per thread -> every weight load
// feeds 2 pk-fma; h_i contribution to layer-1 computed once per thread.
// 32 nodes/block, 320 threads (10 pairs per node).
// ---------------------------------------------------------------------------
__global__ __launch_bounds__(TPB) void layer_kernel(
    const float* __restrict__ pos, const int* __restrict__ srcidx,
    const float* __restrict__ h_in, float* __restrict__ h_out,
    const float* __restrict__ ew1_, const float* __restrict__ eb1_,
    const float* __restrict__ ew2_, const float* __restrict__ eb2_,
    const float* __restrict__ ew3_, const float* __restrict__ eb3_,
    const float* __restrict__ nw1_, const float* __restrict__ nb1_,
    const float* __restrict__ nw2_, const float* __restrict__ nb2_) {
    __shared__ float sm[NPB * KNN * SMSTR];   // 640*17*4 = 43.5 KB

    const auto W1 = c2(ew1_); const auto B1 = c2(eb1_);
    const auto W2 = c2(ew2_); const auto B2 = c2(eb2_);
    const auto W3 = c2(ew3_); const auto B3 = c2(eb3_);
    const auto nw1 = cptr(nw1_); const auto nb1 = cptr(nb1_);
    const auto nw2 = cptr(nw2_); const auto nb2 = cptr(nb2_);

    const int t  = threadIdx.x;
    const int nloc = t / 10;                 // node-local 0..31
    const int q    = t - nloc * 10;          // pair 0..9
    const int i    = blockIdx.x * NPB + nloc;
    const int e0   = i * KNN + 2 * q;

    const int2 jj = *(const int2*)(srcidx + e0);
    const int j0 = jj.x, j1 = jj.y;

    const float pix = pos[3 * (size_t)i + 0];
    const float piy = pos[3 * (size_t)i + 1];
    const float piz = pos[3 * (size_t)i + 2];
    const float ni  = sqrtf(pix * pix + piy * piy + piz * piz);
    const float rni = __fdividef(1.0f, ni + 1e-8f);
    const float oix = pix * rni, oiy = piy * rni, oiz = piz * rni;

    float g0[5], g1[5];
    {
        const float pjx = pos[3 * (size_t)j0 + 0];
        const float pjy = pos[3 * (size_t)j0 + 1];
        const float pjz = pos[3 * (size_t)j0 + 2];
        const float rx = pjx - pix, ry = pjy - piy, rz = pjz - piz;
        const float dist = sqrtf(rx * rx + ry * ry + rz * rz);
        const float rid  = __fdividef(1.0f, dist + 1e-8f);
        const float nj  = sqrtf(pjx * pjx + pjy * pjy + pjz * pjz);
        const float rnj = __fdividef(1.0f, nj + 1e-8f);
        g0[0] = dist; g0[1] = rx * rid; g0[2] = ry * rid; g0[3] = rz * rid;
        g0[4] = oix * (pjx * rnj) + oiy * (pjy * rnj) + oiz * (pjz * rnj);
    }
    {
        const float pjx = pos[3 * (size_t)j1 + 0];
        const float pjy = pos[3 * (size_t)j1 + 1];
        const float pjz = pos[3 * (size_t)j1 + 2];
        const float rx = pjx - pix, ry = pjy - piy, rz = pjz - piz;
        const float dist = sqrtf(rx * rx + ry * ry + rz * rz);
        const float rid  = __fdividef(1.0f, dist + 1e-8f);
        const float nj  = sqrtf(pjx * pjx + pjy * pjy + pjz * pjz);
        const float rnj = __fdividef(1.0f, nj + 1e-8f);
        g1[0] = dist; g1[1] = rx * rid; g1[2] = ry * rid; g1[3] = rz * rid;
        g1[4] = oix * (pjx * rnj) + oiy * (pjy * rnj) + oiz * (pjz * rnj);
    }

    float hi[HD], hj0[HD], hj1[HD];
    {
        const float4* p = (const float4*)(h_in + (size_t)i * HD);
        float4 a = p[0], b = p[1], c = p[2], d = p[3];
        hi[0] = a.x; hi[1] = a.y; hi[2] = a.z; hi[3] = a.w;
        hi[4] = b.x; hi[5] = b.y; hi[6] = b.z; hi[7] = b.w;
        hi[8] = c.x; hi[9] = c.y; hi[10] = c.z; hi[11] = c.w;
        hi[12] = d.x; hi[13] = d.y; hi[14] = d.z; hi[15] = d.w;
    }
    {
        const float4* p = (const float4*)(h_in + (size_t)j0 * HD);
        float4 a = p[0], b = p[1], c = p[2], d = p[3];
        hj0[0] = a.x; hj0[1] = a.y; hj0[2] = a.z; hj0[3] = a.w;
        hj0[4] = b.x; hj0[5] = b.y; hj0[6] = b.z; hj0[7] = b.w;
        hj0[8] = c.x; hj0[9] = c.y; hj0[10] = c.z; hj0[11] = c.w;
        hj0[12] = d.x; hj0[13] = d.y; hj0[14] = d.z; hj0[15] = d.w;
    }
    {
        const float4* p = (const float4*)(h_in + (size_t)j1 * HD);
        float4 a = p[0], b = p[1], c = p[2], d = p[3];
        hj1[0] = a.x; hj1[1] = a.y; hj1[2] = a.z; hj1[3] = a.w;
        hj1[4] = b.x; hj1[5] = b.y; hj1[6] = b.z; hj1[7] = b.w;
        hj1[8] = c.x; hj1[9] = c.y; hj1[10] = c.z; hj1[11] = c.w;
        hj1[12] = d.x; hj1[13] = d.y; hj1[14] = d.z; hj1[15] = d.w;
    }

    // --- layer 1: common = B1 + hi @ W1_a (shared by both edges) ---
    v2f t1b[16];
#pragma unroll
    for (int og = 0; og < 16; ++og) t1b[og] = B1[og];
#pragma unroll
    for (int c = 0; c < HD; ++c) {
        const v2f av = {hi[c], hi[c]};
#pragma unroll
        for (int og = 0; og < 16; ++og)
            t1b[og] += av * W1[c * 16 + og];
    }
    v2f t1a[16];
#pragma unroll
    for (int og = 0; og < 16; ++og) t1a[og] = t1b[og];

    // per-edge hj part: one weight load, two pk-fma
#pragma unroll
    for (int c = 0; c < HD; ++c) {
        const v2f b0 = {hj0[c], hj0[c]};
        const v2f b1 = {hj1[c], hj1[c]};
#pragma unroll
        for (int og = 0; og < 16; ++og) {
            const v2f w = W1[(HD + c) * 16 + og];
            t1a[og] += b0 * w;
            t1b[og] += b1 * w;
        }
    }
#pragma unroll
    for (int r = 0; r < 5; ++r) {
        const v2f ga = {g0[r], g0[r]};
        const v2f gb = {g1[r], g1[r]};
#pragma unroll
        for (int og = 0; og < 16; ++og) {
            const v2f w = W1[(32 + r) * 16 + og];
            t1a[og] += ga * w;
            t1b[og] += gb * w;
        }
    }
#pragma unroll
    for (int og = 0; og < 16; ++og) { t1a[og] = silu2(t1a[og]); t1b[og] = silu2(t1b[og]); }

    // --- layer 2 ---
    v2f t2a[8], t2b[8];
#pragma unroll
    for (int og = 0; og < 8; ++og) { t2a[og] = B2[og]; t2b[og] = B2[og]; }
#pragma unroll
    for (int c = 0; c < 32; ++c) {
        const float a0 = t1a[c >> 1][c & 1];
        const float a1 = t1b[c >> 1][c & 1];
        const v2f a0v = {a0, a0};
        const v2f a1v = {a1, a1};
#pragma unroll
        for (int og = 0; og < 8; ++og) {
            const v2f w = W2[c * 8 + og];
            t2a[og] += a0v * w;
            t2b[og] += a1v * w;
        }
    }
#pragma unroll
    for (int og = 0; og < 8; ++og) { t2a[og] = silu2(t2a[og]); t2b[og] = silu2(t2b[og]); }

    // --- layer 3 -> messages ---
    v2f mva[8], mvb[8];
#pragma unroll
    for (int og = 0; og < 8; ++og) { mva[og] = B3[og]; mvb[og] = B3[og]; }
#pragma unroll
    for (int c = 0; c < HD; ++c) {
        const float a0 = t2a[c >> 1][c & 1];
        const float a1 = t2b[c >> 1][c & 1];
        const v2f a0v = {a0, a0};
        const v2f a1v = {a1, a1};
#pragma unroll
        for (int og = 0; og < 8; ++og) {
            const v2f w = W3[c * 8 + og];
            mva[og] += a0v * w;
            mvb[og] += a1v * w;
        }
    }
    {
        const int el0 = nloc * KNN + 2 * q;
#pragma unroll
        for (int og = 0; og < 8; ++og) {
            sm[el0 * SMSTR + 2 * og + 0] = mva[og][0];
            sm[el0 * SMSTR + 2 * og + 1] = mva[og][1];
            sm[(el0 + 1) * SMSTR + 2 * og + 0] = mvb[og][0];
            sm[(el0 + 1) * SMSTR + 2 * og + 1] = mvb[og][1];
        }
    }

    __syncthreads();   // [S1] messages staged

    // --- reduction: 512 items (32 nodes x 16 feats); threads t<256 take 2 ---
    float rs1 = 0.0f, rm1 = -INFINITY, rs2 = 0.0f, rm2 = -INFINITY;
    float hn1 = 0.0f, hn2 = 0.0f;
    if (t < 256) {
        const int m1 = t, m2 = t + 256;
        const int n1 = m1 >> 4, o1 = m1 & 15;
        const int n2 = m2 >> 4, o2 = m2 & 15;
#pragma unroll
        for (int k = 0; k < KNN; ++k) {
            rs1 += sm[(n1 * KNN + k) * SMSTR + o1];
            rm1 = fmaxf(rm1, sm[(n1 * KNN + k) * SMSTR + o1]);
            rs2 += sm[(n2 * KNN + k) * SMSTR + o2];
            rm2 = fmaxf(rm2, sm[(n2 * KNN + k) * SMSTR + o2]);
        }
        hn1 = h_in[(size_t)blockIdx.x * 512 + m1];
        hn2 = h_in[(size_t)blockIdx.x * 512 + m2];
    }
    __syncthreads();   // [S2] sm reads done; safe to alias

    float* hi_s = sm;           // [512]
    float* me_s = sm + 512;     // [512]
    float* mx_s = sm + 1024;    // [512]
    float* u1_s = sm + 1536;    // [32*40]

    if (t < 256) {
        hi_s[t]       = hn1;  hi_s[t + 256] = hn2;
        me_s[t]       = rs1 / 20.0f;  me_s[t + 256] = rs2 / 20.0f;
        mx_s[t]       = rm1;  mx_s[t + 256] = rm2;
    }
    __syncthreads();   // [S3]

    if (t < 256) {
#pragma unroll
        for (int item = 0; item < 2; ++item) {
            const int m = t + item * 256;
            const int n = m >> 4, o = m & 15;
            float o0 = nb1[o], o1 = nb1[o + 16];
#pragma unroll
            for (int c = 0; c < HD; ++c) {
                const float hc = hi_s[n * HD + c];
                const float mc = me_s[n * HD + c];
                const float xc = mx_s[n * HD + c];
                o0 += hc * nw1[c * 32 + o]      + mc * nw1[(HD + c) * 32 + o]
                    + xc * nw1[(2 * HD + c) * 32 + o];
                o1 += hc * nw1[c * 32 + o + 16] + mc * nw1[(HD + c) * 32 + o + 16]
                    + xc * nw1[(2 * HD + c) * 32 + o + 16];
            }
            u1_s[n * 40 + o]      = silu_f(o0);
            u1_s[n * 40 + o + 16] = silu_f(o1);
        }
    }
    __syncthreads();   // [S4]

    if (t < 256) {
        {
            const int m = t, n = m >> 4, o = m & 15;
            float acc = nb2[o];
#pragma unroll
            for (int c = 0; c < 32; ++c) acc += u1_s[n * 40 + c] * nw2[c * HD + o];
            h_out[(size_t)blockIdx.x * 512 + m] = hn1 + acc;
        }
        {
            const int m = t + 256, n = m >> 4, o = m & 15;
            float acc = nb2[o];
#pragma unroll
            for (int c = 0; c < 32; ++c) acc += u1_s[n * 40 + c] * nw2[c * HD + o];
            h_out[(size_t)blockIdx.x * 512 + m] = hn2 + acc;
        }
    }
}

// ---------------------------------------------------------------------------
// output head (unchanged)
// ---------------------------------------------------------------------------
__global__ __launch_bounds__(256) void out_kernel(
    const float* __restrict__ h,
    const float* __restrict__ ow1_, const float* __restrict__ ob1_,
    const float* __restrict__ ow2_, const float* __restrict__ ob2_,
    const float* __restrict__ ow3_, const float* __restrict__ ob3_,
    float* __restrict__ out) {
    const auto ow1 = cptr(ow1_); const auto ob1 = cptr(ob1_);
    const auto ow2 = cptr(ow2_); const auto ob2 = cptr(ob2_);
    const auto ow3 = cptr(ow3_); const auto ob3 = cptr(ob3_);
    const int i = blockIdx.x * 256 + threadIdx.x;
    if (i >= NTOT) return;

    float hv[HD];
    {
        const float4* p = (const float4*)(h + (size_t)i * HD);
        float4 a = p[0], b = p[1], c = p[2], d = p[3];
        hv[0] = a.x; hv[1] = a.y; hv[2] = a.z; hv[3] = a.w;
        hv[4] = b.x; hv[5] = b.y; hv[6] = b.z; hv[7] = b.w;
        hv[8] = c.x; hv[9] = c.y; hv[10] = c.z; hv[11] = c.w;
        hv[12] = d.x; hv[13] = d.y; hv[14] = d.z; hv[15] = d.w;
    }

    float t1[HD];
#pragma unroll
    for (int o = 0; o < HD; ++o) t1[o] = ob1[o];
#pragma unroll
    for (int c = 0; c < HD; ++c) {
        const float a = hv[c];
#pragma unroll
        for (int o = 0; o < HD; ++o) t1[o] += a * ow1[c * HD + o];
    }
#pragma unroll
    for (int o = 0; o < HD; ++o) t1[o] = silu_f(t1[o]);

    float t2[8];
#pragma unroll
    for (int o = 0; o < 8; ++o) t2[o] = ob2[o];
#pragma unroll
    for (int c = 0; c < HD; ++c) {
        const float a = t1[c];
#pragma unroll
        for (int o = 0; o < 8; ++o) t2[o] += a * ow2[c * 8 + o];
    }
#pragma unroll
    for (int o = 0; o < 8; ++o) t2[o] = silu_f(t2[o]);

    float r0 = ob3[0], r1 = ob3[1], r2 = ob3[2];
#pragma unroll
    for (int c = 0; c < 8; ++c) {
        r0 += t2[c] * ow3[c * 3 + 0];
        r1 += t2[c] * ow3[c * 3 + 1];
        r2 += t2[c] * ow3[c * 3 + 2];
    }
    out[3 * (size_t)i + 0] = r0;
    out[3 * (size_t)i + 1] = r1;
    out[3 * (size_t)i + 2] = r2;
}

// ---------------------------------------------------------------------------
extern "C" void kernel_launch(void* const* d_in, const int* in_sizes, int n_in,
                              void* d_out, int out_size, void* d_ws, size_t ws_size,
                              hipStream_t stream) {
    const float* pos   = (const float*)d_in[0];
    const float* pe_w1 = (const float*)d_in[1];
    const float* pe_b1 = (const float*)d_in[2];
    const float* pe_w2 = (const float*)d_in[3];
    const float* pe_b2 = (const float*)d_in[4];
    const float* ew1   = (const float*)d_in[5];
    const float* eb1   = (const float*)d_in[6];
    const float* ew2   = (const float*)d_in[7];
    const float* eb2   = (const float*)d_in[8];
    const float* ew3   = (const float*)d_in[9];
    const float* eb3   = (const float*)d_in[10];
    const float* nw1   = (const float*)d_in[11];
    const float* nb1   = (const float*)d_in[12];
    const float* nw2   = (const float*)d_in[13];
    const float* nb2   = (const float*)d_in[14];
    const float* ow1   = (const float*)d_in[15];
    const float* ob1   = (const float*)d_in[16];
    const float* ow2   = (const float*)d_in[17];
    const float* ob2   = (const float*)d_in[18];
    const float* ow3   = (const float*)d_in[19];
    const float* ob3   = (const float*)d_in[20];

    char* ws = (char*)d_ws;
    int*   srcidx = (int*)ws;                                     // NTOT*KNN ints
    float* h0 = (float*)(ws + (size_t)NTOT * KNN * sizeof(int));
    float* h1 = h0 + (size_t)NTOT * HD;

    knn_kernel<<<NGRAPH * 8, 512, 0, stream>>>(pos, srcidx);
    embed_kernel<<<NTOT / 256, 256, 0, stream>>>(pos, pe_w1, pe_b1, pe_w2, pe_b2, h0);

    const int lblocks = NTOT / NPB;   // 2048
    for (int l = 0; l < 4; ++l) {
        const float* hin  = (l & 1) ? h1 : h0;
        float*       hout = (l & 1) ? h0 : h1;
        layer_kernel<<<lblocks, TPB, 0, stream>>>(
            pos, srcidx, hin, hout,
            ew1 + (size_t)l * 37 * 32, eb1 + (size_t)l * 32,
            ew2 + (size_t)l * 32 * 16, eb2 + (size_t)l * 16,
            ew3 + (size_t)l * 16 * 16, eb3 + (size_t)l * 16,
            nw1 + (size_t)l * 48 * 32, nb1 + (size_t)l * 32,
            nw2 + (size_t)l * 32 * 16, nb2 + (size_t)l * 16);
    }

    out_kernel<<<NTOT / 256, 256, 0, stream>>>(h0, ow1, ob1, ow2, ob2, ow3, ob3,
                                               (float*)d_out);
}